// Round 1
// baseline (1187.657 us; speedup 1.0000x reference)
//
#include <hip/hip_runtime.h>
#include <math.h>

#define N_NODES 50000
#define N_EDGES 800000
#define HID 128
#define OUTC 64
#define NLAYERS 8

// ---------------- CSR build ----------------

__global__ void k_zero(int* __restrict__ p, int n) {
    int i = blockIdx.x * blockDim.x + threadIdx.x;
    if (i < n) p[i] = 0;
}

__global__ void k_count(const int* __restrict__ dst, int* __restrict__ deg, int E) {
    int e = blockIdx.x * blockDim.x + threadIdx.x;
    if (e < E) atomicAdd(&deg[dst[e]], 1);
}

// single-block scan: reads deg from `cur`, writes offsets to `off`, rewrites `cur` to a copy of off
__global__ __launch_bounds__(1024) void k_scan(int* __restrict__ cur, int* __restrict__ off, int n) {
    __shared__ int sums[1024];
    const int t = threadIdx.x;
    const int chunk = (n + 1023) / 1024;
    int lo = t * chunk; if (lo > n) lo = n;
    int hi = lo + chunk; if (hi > n) hi = n;
    int s = 0;
    for (int i = lo; i < hi; i++) s += cur[i];
    sums[t] = s;
    __syncthreads();
    for (int d = 1; d < 1024; d <<= 1) {
        int v = (t >= d) ? sums[t - d] : 0;
        __syncthreads();
        sums[t] += v;
        __syncthreads();
    }
    int base = (t == 0) ? 0 : sums[t - 1];
    for (int i = lo; i < hi; i++) {
        int d = cur[i];
        off[i] = base;
        cur[i] = base;
        base += d;
    }
    if (t == 1023) off[n] = sums[1023];
}

__global__ void k_scatter(const int* __restrict__ src, const int* __restrict__ dst,
                          const float* __restrict__ w, int* __restrict__ cursor,
                          int* __restrict__ e_src, float* __restrict__ e_w, int E) {
    int e = blockIdx.x * blockDim.x + threadIdx.x;
    if (e < E) {
        int d = dst[e];
        int pos = atomicAdd(&cursor[d], 1);
        e_src[pos] = src[e];
        e_w[pos] = w[e];
    }
}

// ---------------- SPMM (CSR gather, one wave per node) ----------------
// C = channels (128 or 64)
// MODE 0: out = relu(acc + bias(aux)), also duplicated into out2 (x0 copy)
// MODE 1: out = 0.5*acc + 0.5*x0(aux)
// MODE 2: out = acc + bias(aux)           (C==64 final layer)
template <int C, int MODE>
__global__ __launch_bounds__(256) void k_spmm(
    const int* __restrict__ off, const int* __restrict__ e_src, const float* __restrict__ e_w,
    const float* __restrict__ feats, const float* __restrict__ aux,
    float* __restrict__ out, float* __restrict__ out2)
{
    const int wave = threadIdx.x >> 6;
    const int lane = threadIdx.x & 63;
    const int node = blockIdx.x * 4 + wave;
    if (node >= N_NODES) return;
    const int lo = off[node], hi = off[node + 1];

    if constexpr (C == 128) {
        float ax = 0.f, ay = 0.f;
        const int c = lane * 2;
        int i = lo;
        for (; i + 4 <= hi; i += 4) {
            int s0 = e_src[i], s1 = e_src[i + 1], s2 = e_src[i + 2], s3 = e_src[i + 3];
            float w0 = e_w[i], w1 = e_w[i + 1], w2 = e_w[i + 2], w3 = e_w[i + 3];
            float2 v0 = *(const float2*)(feats + (size_t)s0 * 128 + c);
            float2 v1 = *(const float2*)(feats + (size_t)s1 * 128 + c);
            float2 v2 = *(const float2*)(feats + (size_t)s2 * 128 + c);
            float2 v3 = *(const float2*)(feats + (size_t)s3 * 128 + c);
            ax = fmaf(w0, v0.x, ax); ay = fmaf(w0, v0.y, ay);
            ax = fmaf(w1, v1.x, ax); ay = fmaf(w1, v1.y, ay);
            ax = fmaf(w2, v2.x, ax); ay = fmaf(w2, v2.y, ay);
            ax = fmaf(w3, v3.x, ax); ay = fmaf(w3, v3.y, ay);
        }
        for (; i < hi; ++i) {
            int s = e_src[i]; float w = e_w[i];
            float2 v = *(const float2*)(feats + (size_t)s * 128 + c);
            ax = fmaf(w, v.x, ax); ay = fmaf(w, v.y, ay);
        }
        if constexpr (MODE == 0) {
            float r0 = fmaxf(ax + aux[c], 0.f);
            float r1 = fmaxf(ay + aux[c + 1], 0.f);
            float2 r; r.x = r0; r.y = r1;
            *(float2*)(out  + (size_t)node * 128 + c) = r;
            *(float2*)(out2 + (size_t)node * 128 + c) = r;
        } else {
            float2 x0v = *(const float2*)(aux + (size_t)node * 128 + c);
            float2 r; r.x = 0.5f * ax + 0.5f * x0v.x; r.y = 0.5f * ay + 0.5f * x0v.y;
            *(float2*)(out + (size_t)node * 128 + c) = r;
        }
    } else { // C == 64, MODE 2
        float a = 0.f;
        int i = lo;
        for (; i + 4 <= hi; i += 4) {
            int s0 = e_src[i], s1 = e_src[i + 1], s2 = e_src[i + 2], s3 = e_src[i + 3];
            float w0 = e_w[i], w1 = e_w[i + 1], w2 = e_w[i + 2], w3 = e_w[i + 3];
            float v0 = feats[(size_t)s0 * 64 + lane];
            float v1 = feats[(size_t)s1 * 64 + lane];
            float v2 = feats[(size_t)s2 * 64 + lane];
            float v3 = feats[(size_t)s3 * 64 + lane];
            a = fmaf(w0, v0, a); a = fmaf(w1, v1, a);
            a = fmaf(w2, v2, a); a = fmaf(w3, v3, a);
        }
        for (; i < hi; ++i) {
            int s = e_src[i]; float w = e_w[i];
            a = fmaf(w, feats[(size_t)s * 64 + lane], a);
        }
        out[(size_t)node * 64 + lane] = a + aux[lane];
    }
}

// ---------------- GEMM: out[M x N] = A[M x 128] @ W[128 x N], optional GCNII epilogue ----------------
// MODE 0: out = A@W
// MODE 1: out = relu((1-beta)*A + beta*(A@W))   (elementwise on the same tile, A re-read from LDS)
template <int N, int MODE>
__global__ __launch_bounds__(256) void k_gemm(
    const float* __restrict__ A, const float* __restrict__ W,
    float* __restrict__ out, float beta, int M)
{
    constexpr int CPT = N / 32; // cols per thread (4 for N=128, 2 for N=64)
    __shared__ float As[32][128];
    const int tid = threadIdx.x;
    const int row0 = blockIdx.x * 32;

    { // stage 32x128 A-tile (zero-pad tail rows)
        const float4* srcp = (const float4*)(A + (size_t)row0 * 128);
        float4* dl = (float4*)(&As[0][0]);
        #pragma unroll
        for (int it = 0; it < 4; it++) {
            int idx = tid + it * 256;     // float4 index, 32 float4 per row
            int r = idx >> 5;
            float4 v;
            if (row0 + r < M) v = srcp[idx];
            else v = make_float4(0.f, 0.f, 0.f, 0.f);
            dl[idx] = v;
        }
    }
    __syncthreads();

    const int rg = tid >> 5;        // 0..7 -> rows rg*4 .. rg*4+3
    const int cg = tid & 31;
    const int c0 = cg * CPT;

    float acc[4][CPT];
    #pragma unroll
    for (int i = 0; i < 4; i++)
        #pragma unroll
        for (int j = 0; j < CPT; j++) acc[i][j] = 0.f;

    #pragma unroll 4
    for (int k = 0; k < 128; k++) {
        float a0 = As[rg * 4 + 0][k];
        float a1 = As[rg * 4 + 1][k];
        float a2 = As[rg * 4 + 2][k];
        float a3 = As[rg * 4 + 3][k];
        float w[CPT];
        #pragma unroll
        for (int j = 0; j < CPT; j++) w[j] = W[(size_t)k * N + c0 + j];
        #pragma unroll
        for (int j = 0; j < CPT; j++) {
            acc[0][j] = fmaf(a0, w[j], acc[0][j]);
            acc[1][j] = fmaf(a1, w[j], acc[1][j]);
            acc[2][j] = fmaf(a2, w[j], acc[2][j]);
            acc[3][j] = fmaf(a3, w[j], acc[3][j]);
        }
    }

    const float omb = 1.f - beta;
    #pragma unroll
    for (int i = 0; i < 4; i++) {
        int r = row0 + rg * 4 + i;
        if (r < M) {
            #pragma unroll
            for (int j = 0; j < CPT; j++) {
                float v = acc[i][j];
                if constexpr (MODE == 1) {
                    float t = As[rg * 4 + i][c0 + j];
                    v = fmaxf(omb * t + beta * v, 0.f);
                }
                out[(size_t)r * N + c0 + j] = v;
            }
        }
    }
}

// ---------------- launch ----------------

extern "C" void kernel_launch(void* const* d_in, const int* in_sizes, int n_in,
                              void* d_out, int out_size, void* d_ws, size_t ws_size,
                              hipStream_t stream)
{
    const float* x     = (const float*)d_in[0];
    const int*   ei    = (const int*)d_in[1];
    const float* ew    = (const float*)d_in[2];
    const float* W_in  = (const float*)d_in[3];
    const float* b_in  = (const float*)d_in[4];
    const float* W_lay = (const float*)d_in[5];
    const float* W_out = (const float*)d_in[6];
    const float* b_out = (const float*)d_in[7];
    float* out = (float*)d_out;

    const int* src = ei;
    const int* dst = ei + N_EDGES;

    char* p = (char*)d_ws;
    auto alloc = [&](size_t bytes) -> char* {
        char* q = p;
        p += (bytes + 255) & ~(size_t)255;
        return q;
    };
    int*   cursor = (int*)alloc((size_t)N_NODES * 4);
    int*   off    = (int*)alloc((size_t)(N_NODES + 1) * 4);
    int*   e_src  = (int*)alloc((size_t)N_EDGES * 4);
    float* e_w    = (float*)alloc((size_t)N_EDGES * 4);
    float* bufT   = (float*)alloc((size_t)N_NODES * HID * 4);
    float* bufH   = (float*)alloc((size_t)N_NODES * HID * 4);
    float* bufX0  = (float*)alloc((size_t)N_NODES * HID * 4);

    // CSR build
    k_zero<<<(N_NODES + 255) / 256, 256, 0, stream>>>(cursor, N_NODES);
    k_count<<<(N_EDGES + 255) / 256, 256, 0, stream>>>(dst, cursor, N_EDGES);
    k_scan<<<1, 1024, 0, stream>>>(cursor, off, N_NODES);
    k_scatter<<<(N_EDGES + 255) / 256, 256, 0, stream>>>(src, dst, ew, cursor, e_src, e_w, N_EDGES);

    const int gemmGrid = (N_NODES + 31) / 32;
    const int spmmGrid = (N_NODES + 3) / 4;

    // z = x @ W_in  -> bufT
    k_gemm<128, 0><<<gemmGrid, 256, 0, stream>>>(x, W_in, bufT, 0.f, N_NODES);
    // h = relu(spmm(z) + b_in) -> bufH, copy -> bufX0
    k_spmm<128, 0><<<spmmGrid, 256, 0, stream>>>(off, e_src, e_w, bufT, b_in, bufH, bufX0);

    for (int l = 0; l < NLAYERS; l++) {
        float beta = logf(1.0f / (float)(l + 1) + 1.0f);
        // t = 0.5*spmm(h) + 0.5*x0 -> bufT
        k_spmm<128, 1><<<spmmGrid, 256, 0, stream>>>(off, e_src, e_w, bufH, bufX0, bufT, nullptr);
        // h = relu((1-beta)*t + beta*(t @ W_l)) -> bufH
        k_gemm<128, 1><<<gemmGrid, 256, 0, stream>>>(bufT, W_lay + (size_t)l * HID * HID, bufH, beta, N_NODES);
    }

    // y = h @ W_out -> bufT (N=64)
    k_gemm<64, 0><<<gemmGrid, 256, 0, stream>>>(bufH, W_out, bufT, 0.f, N_NODES);
    // out = spmm(y) + b_out
    k_spmm<64, 2><<<spmmGrid, 256, 0, stream>>>(off, e_src, e_w, bufT, b_out, out, nullptr);
}

// Round 2
// 1029.750 us; speedup vs baseline: 1.1533x; 1.1533x over previous
//
#include <hip/hip_runtime.h>
#include <math.h>

#define N_NODES 50000
#define N_EDGES 800000
#define HID 128
#define OUTC 64
#define NLAYERS 8

#define SCAN_B 64
#define SCAN_T 256
#define SCAN_C 4   // 64*256*4 = 65536 >= 50000

// ---------------- CSR build ----------------

__global__ void k_zero(int* __restrict__ p, int n) {
    int i = blockIdx.x * blockDim.x + threadIdx.x;
    if (i < n) p[i] = 0;
}

__global__ void k_count(const int* __restrict__ dst, int* __restrict__ deg, int E) {
    int e = blockIdx.x * blockDim.x + threadIdx.x;
    if (e < E) atomicAdd(&deg[dst[e]], 1);
}

// block-level partial sums of deg
__global__ __launch_bounds__(SCAN_T) void k_scanA(const int* __restrict__ deg, int* __restrict__ bsum) {
    __shared__ int red[SCAN_T];
    const int t = threadIdx.x, b = blockIdx.x;
    const int g = b * SCAN_T + t;
    int lo = g * SCAN_C; if (lo > N_NODES) lo = N_NODES;
    int hi = lo + SCAN_C; if (hi > N_NODES) hi = N_NODES;
    int s = 0;
    for (int i = lo; i < hi; i++) s += deg[i];
    red[t] = s;
    __syncthreads();
    for (int d = SCAN_T / 2; d > 0; d >>= 1) {
        if (t < d) red[t] += red[t + d];
        __syncthreads();
    }
    if (t == 0) bsum[b] = red[0];
}

// full exclusive scan: reads deg from cur, writes off[] and cursor copy (cur)
__global__ __launch_bounds__(SCAN_T) void k_scanB(int* __restrict__ cur, int* __restrict__ off,
                                                  const int* __restrict__ bsum) {
    __shared__ int pre[SCAN_T];
    __shared__ int baseSh;
    const int t = threadIdx.x, b = blockIdx.x;
    const int g = b * SCAN_T + t;
    int lo = g * SCAN_C; if (lo > N_NODES) lo = N_NODES;
    int hi = lo + SCAN_C; if (hi > N_NODES) hi = N_NODES;
    int s = 0;
    for (int i = lo; i < hi; i++) s += cur[i];
    pre[t] = s;
    if (t == 0) {
        int acc = 0;
        for (int j = 0; j < b; j++) acc += bsum[j];
        baseSh = acc;
    }
    __syncthreads();
    for (int d = 1; d < SCAN_T; d <<= 1) {
        int v = (t >= d) ? pre[t - d] : 0;
        __syncthreads();
        pre[t] += v;
        __syncthreads();
    }
    int running = baseSh + pre[t] - s;   // exclusive prefix for this thread's chunk
    for (int i = lo; i < hi; i++) {
        int d = cur[i];
        off[i] = running;
        cur[i] = running;
        running += d;
        if (i == N_NODES - 1) off[N_NODES] = running;
    }
}

__global__ void k_scatter(const int* __restrict__ src, const int* __restrict__ dst,
                          const float* __restrict__ w, int* __restrict__ cursor,
                          int* __restrict__ e_src, float* __restrict__ e_w, int E) {
    int e = blockIdx.x * blockDim.x + threadIdx.x;
    if (e < E) {
        int d = dst[e];
        int pos = atomicAdd(&cursor[d], 1);
        e_src[pos] = src[e];
        e_w[pos] = w[e];
    }
}

// ---------------- shared gather helper (128-ch, 2 ch/lane) ----------------

__device__ __forceinline__ void gather128(const int* __restrict__ e_src, const float* __restrict__ e_w,
                                          int lo, int hi, const float* __restrict__ feats, int c,
                                          float& ax, float& ay)
{
    int i = lo;
    for (; i + 4 <= hi; i += 4) {
        int s0 = e_src[i], s1 = e_src[i + 1], s2 = e_src[i + 2], s3 = e_src[i + 3];
        float w0 = e_w[i], w1 = e_w[i + 1], w2 = e_w[i + 2], w3 = e_w[i + 3];
        float2 v0 = *(const float2*)(feats + (size_t)s0 * 128 + c);
        float2 v1 = *(const float2*)(feats + (size_t)s1 * 128 + c);
        float2 v2 = *(const float2*)(feats + (size_t)s2 * 128 + c);
        float2 v3 = *(const float2*)(feats + (size_t)s3 * 128 + c);
        ax = fmaf(w0, v0.x, ax); ay = fmaf(w0, v0.y, ay);
        ax = fmaf(w1, v1.x, ax); ay = fmaf(w1, v1.y, ay);
        ax = fmaf(w2, v2.x, ax); ay = fmaf(w2, v2.y, ay);
        ax = fmaf(w3, v3.x, ax); ay = fmaf(w3, v3.y, ay);
    }
    for (; i < hi; ++i) {
        int s = e_src[i]; float w = e_w[i];
        float2 v = *(const float2*)(feats + (size_t)s * 128 + c);
        ax = fmaf(w, v.x, ax); ay = fmaf(w, v.y, ay);
    }
}

// ---------------- standalone SPMM ----------------
// MODE 0: out = relu(acc + bias(aux)), duplicated into out2 (x0 copy)    (C=128)
// MODE 2: out = acc + bias(aux)                                          (C=64)
template <int C, int MODE>
__global__ __launch_bounds__(256) void k_spmm(
    const int* __restrict__ off, const int* __restrict__ e_src, const float* __restrict__ e_w,
    const float* __restrict__ feats, const float* __restrict__ aux,
    float* __restrict__ out, float* __restrict__ out2)
{
    const int wave = threadIdx.x >> 6;
    const int lane = threadIdx.x & 63;
    const int node = blockIdx.x * 4 + wave;
    if (node >= N_NODES) return;
    const int lo = off[node], hi = off[node + 1];

    if constexpr (C == 128) {
        float ax = 0.f, ay = 0.f;
        const int c = lane * 2;
        gather128(e_src, e_w, lo, hi, feats, c, ax, ay);
        float r0 = fmaxf(ax + aux[c], 0.f);
        float r1 = fmaxf(ay + aux[c + 1], 0.f);
        float2 r; r.x = r0; r.y = r1;
        *(float2*)(out  + (size_t)node * 128 + c) = r;
        *(float2*)(out2 + (size_t)node * 128 + c) = r;
    } else { // C == 64, MODE 2
        float a = 0.f;
        int i = lo;
        for (; i + 4 <= hi; i += 4) {
            int s0 = e_src[i], s1 = e_src[i + 1], s2 = e_src[i + 2], s3 = e_src[i + 3];
            float w0 = e_w[i], w1 = e_w[i + 1], w2 = e_w[i + 2], w3 = e_w[i + 3];
            float v0 = feats[(size_t)s0 * 64 + lane];
            float v1 = feats[(size_t)s1 * 64 + lane];
            float v2 = feats[(size_t)s2 * 64 + lane];
            float v3 = feats[(size_t)s3 * 64 + lane];
            a = fmaf(w0, v0, a); a = fmaf(w1, v1, a);
            a = fmaf(w2, v2, a); a = fmaf(w3, v3, a);
        }
        for (; i < hi; ++i) {
            int s = e_src[i]; float w = e_w[i];
            a = fmaf(w, feats[(size_t)s * 64 + lane], a);
        }
        out[(size_t)node * 64 + lane] = a + aux[lane];
    }
}

// ---------------- standalone GEMM: out[M x N] = A[M x 128] @ W[128 x N] ----------------
template <int N>
__global__ __launch_bounds__(256) void k_gemm(
    const float* __restrict__ A, const float* __restrict__ W,
    float* __restrict__ out, int M)
{
    constexpr int CPT = N / 32;
    __shared__ float As[32][128];
    const int tid = threadIdx.x;
    const int row0 = blockIdx.x * 32;

    {
        const float4* srcp = (const float4*)(A + (size_t)row0 * 128);
        float4* dl = (float4*)(&As[0][0]);
        #pragma unroll
        for (int it = 0; it < 4; it++) {
            int idx = tid + it * 256;
            int r = idx >> 5;
            float4 v;
            if (row0 + r < M) v = srcp[idx];
            else v = make_float4(0.f, 0.f, 0.f, 0.f);
            dl[idx] = v;
        }
    }
    __syncthreads();

    const int rg = tid >> 5;
    const int c0 = (tid & 31) * CPT;

    float acc[4][CPT];
    #pragma unroll
    for (int i = 0; i < 4; i++)
        #pragma unroll
        for (int j = 0; j < CPT; j++) acc[i][j] = 0.f;

    #pragma unroll 4
    for (int k = 0; k < 128; k++) {
        float a0 = As[rg * 4 + 0][k];
        float a1 = As[rg * 4 + 1][k];
        float a2 = As[rg * 4 + 2][k];
        float a3 = As[rg * 4 + 3][k];
        float w[CPT];
        if constexpr (CPT == 4) {
            float4 wv = *(const float4*)(W + (size_t)k * N + c0);
            w[0] = wv.x; w[1] = wv.y; w[2] = wv.z; w[3] = wv.w;
        } else {
            float2 wv = *(const float2*)(W + (size_t)k * N + c0);
            w[0] = wv.x; w[1] = wv.y;
        }
        #pragma unroll
        for (int j = 0; j < CPT; j++) {
            acc[0][j] = fmaf(a0, w[j], acc[0][j]);
            acc[1][j] = fmaf(a1, w[j], acc[1][j]);
            acc[2][j] = fmaf(a2, w[j], acc[2][j]);
            acc[3][j] = fmaf(a3, w[j], acc[3][j]);
        }
    }

    #pragma unroll
    for (int i = 0; i < 4; i++) {
        int r = row0 + rg * 4 + i;
        if (r < M) {
            #pragma unroll
            for (int j = 0; j < CPT; j++)
                out[(size_t)r * N + c0 + j] = acc[i][j];
        }
    }
}

// ---------------- fused layer: h_out = relu((1-beta)*t + beta*(t @ W)),  t = 0.5*spmm(h_in) + 0.5*x0 ----------------
// phase 1: spmm writes t directly into the LDS A-tile (each wave handles 8 nodes)
// phase 2: register-blocked GEMM over the LDS tile with the GCNII epilogue
__global__ __launch_bounds__(256) void k_layer(
    const int* __restrict__ off, const int* __restrict__ e_src, const float* __restrict__ e_w,
    const float* __restrict__ h_in, const float* __restrict__ x0, const float* __restrict__ W,
    float* __restrict__ h_out, float beta)
{
    __shared__ float As[32][128];
    const int tid = threadIdx.x;
    const int wave = tid >> 6, lane = tid & 63;
    const int row0 = blockIdx.x * 32;
    const int c = lane * 2;

    // phase 1: spmm -> t -> LDS
    #pragma unroll 1
    for (int i = 0; i < 8; i++) {
        const int r = wave * 8 + i;
        const int node = row0 + r;
        float ax = 0.f, ay = 0.f;
        if (node < N_NODES) {
            const int lo = off[node], hi = off[node + 1];
            gather128(e_src, e_w, lo, hi, h_in, c, ax, ay);
            float2 x0v = *(const float2*)(x0 + (size_t)node * 128 + c);
            ax = 0.5f * ax + 0.5f * x0v.x;
            ay = 0.5f * ay + 0.5f * x0v.y;
        }
        float2 t; t.x = ax; t.y = ay;
        *(float2*)(&As[r][c]) = t;
    }
    __syncthreads();

    // phase 2: gemm + epilogue
    const int rg = tid >> 5;
    const int c0 = (tid & 31) * 4;

    float acc[4][4];
    #pragma unroll
    for (int i = 0; i < 4; i++)
        #pragma unroll
        for (int j = 0; j < 4; j++) acc[i][j] = 0.f;

    #pragma unroll 4
    for (int k = 0; k < 128; k++) {
        float a0 = As[rg * 4 + 0][k];
        float a1 = As[rg * 4 + 1][k];
        float a2 = As[rg * 4 + 2][k];
        float a3 = As[rg * 4 + 3][k];
        float4 wv = *(const float4*)(W + (size_t)k * 128 + c0);
        float w[4] = {wv.x, wv.y, wv.z, wv.w};
        #pragma unroll
        for (int j = 0; j < 4; j++) {
            acc[0][j] = fmaf(a0, w[j], acc[0][j]);
            acc[1][j] = fmaf(a1, w[j], acc[1][j]);
            acc[2][j] = fmaf(a2, w[j], acc[2][j]);
            acc[3][j] = fmaf(a3, w[j], acc[3][j]);
        }
    }

    const float omb = 1.f - beta;
    #pragma unroll
    for (int i = 0; i < 4; i++) {
        int r = row0 + rg * 4 + i;
        if (r < N_NODES) {
            #pragma unroll
            for (int j = 0; j < 4; j++) {
                float t = As[rg * 4 + i][c0 + j];
                float v = fmaxf(omb * t + beta * acc[i][j], 0.f);
                out_store:
                h_out[(size_t)r * 128 + c0 + j] = v;
            }
        }
    }
}

// ---------------- launch ----------------

extern "C" void kernel_launch(void* const* d_in, const int* in_sizes, int n_in,
                              void* d_out, int out_size, void* d_ws, size_t ws_size,
                              hipStream_t stream)
{
    const float* x     = (const float*)d_in[0];
    const int*   ei    = (const int*)d_in[1];
    const float* ew    = (const float*)d_in[2];
    const float* W_in  = (const float*)d_in[3];
    const float* b_in  = (const float*)d_in[4];
    const float* W_lay = (const float*)d_in[5];
    const float* W_out = (const float*)d_in[6];
    const float* b_out = (const float*)d_in[7];
    float* out = (float*)d_out;

    const int* src = ei;
    const int* dst = ei + N_EDGES;

    char* p = (char*)d_ws;
    auto alloc = [&](size_t bytes) -> char* {
        char* q = p;
        p += (bytes + 255) & ~(size_t)255;
        return q;
    };
    int*   cursor = (int*)alloc((size_t)N_NODES * 4);
    int*   off    = (int*)alloc((size_t)(N_NODES + 1) * 4);
    int*   e_src  = (int*)alloc((size_t)N_EDGES * 4);
    float* e_w    = (float*)alloc((size_t)N_EDGES * 4);
    int*   bsum   = (int*)alloc((size_t)SCAN_B * 4);
    float* bufT   = (float*)alloc((size_t)N_NODES * HID * 4);
    float* bufH   = (float*)alloc((size_t)N_NODES * HID * 4);
    float* bufX0  = (float*)alloc((size_t)N_NODES * HID * 4);

    // CSR build
    k_zero<<<(N_NODES + 255) / 256, 256, 0, stream>>>(cursor, N_NODES);
    k_count<<<(N_EDGES + 255) / 256, 256, 0, stream>>>(dst, cursor, N_EDGES);
    k_scanA<<<SCAN_B, SCAN_T, 0, stream>>>(cursor, bsum);
    k_scanB<<<SCAN_B, SCAN_T, 0, stream>>>(cursor, off, bsum);
    k_scatter<<<(N_EDGES + 255) / 256, 256, 0, stream>>>(src, dst, ew, cursor, e_src, e_w, N_EDGES);

    const int gemmGrid = (N_NODES + 31) / 32;
    const int spmmGrid = (N_NODES + 3) / 4;

    // z = x @ W_in  -> bufT
    k_gemm<128><<<gemmGrid, 256, 0, stream>>>(x, W_in, bufT, N_NODES);
    // h = relu(spmm(z) + b_in) -> bufH, copy -> bufX0
    k_spmm<128, 0><<<spmmGrid, 256, 0, stream>>>(off, e_src, e_w, bufT, b_in, bufH, bufX0);

    // 8 fused layers, ping-pong bufH <-> bufT
    float* hin = bufH;
    float* hout = bufT;
    for (int l = 0; l < NLAYERS; l++) {
        float beta = logf(1.0f / (float)(l + 1) + 1.0f);
        k_layer<<<gemmGrid, 256, 0, stream>>>(off, e_src, e_w, hin, bufX0,
                                              W_lay + (size_t)l * HID * HID, hout, beta);
        float* tmp = hin; hin = hout; hout = tmp;
    }
    // after 8 layers h is in bufH (hin)

    // y = h @ W_out -> bufT area (hout)
    k_gemm<64><<<gemmGrid, 256, 0, stream>>>(hin, W_out, hout, N_NODES);
    // out = spmm(y) + b_out
    k_spmm<64, 2><<<spmmGrid, 256, 0, stream>>>(off, e_src, e_w, hout, b_out, out, nullptr);
}

// Round 3
// 1000.333 us; speedup vs baseline: 1.1873x; 1.0294x over previous
//
#include <hip/hip_runtime.h>
#include <math.h>

#define N_NODES 50000
#define N_EDGES 800000
#define HID 128
#define OUTC 64
#define NLAYERS 8

#define SCAN_B 64
#define SCAN_T 256
#define SCAN_C 4   // 64*256*4 = 65536 >= 50000

// ---------------- CSR build ----------------

__global__ void k_zero(int* __restrict__ p, int n) {
    int i = blockIdx.x * blockDim.x + threadIdx.x;
    if (i < n) p[i] = 0;
}

__global__ void k_count(const int* __restrict__ dst, int* __restrict__ deg, int E) {
    int e = blockIdx.x * blockDim.x + threadIdx.x;
    if (e < E) atomicAdd(&deg[dst[e]], 1);
}

__global__ __launch_bounds__(SCAN_T) void k_scanA(const int* __restrict__ deg, int* __restrict__ bsum) {
    __shared__ int red[SCAN_T];
    const int t = threadIdx.x, b = blockIdx.x;
    const int g = b * SCAN_T + t;
    int lo = g * SCAN_C; if (lo > N_NODES) lo = N_NODES;
    int hi = lo + SCAN_C; if (hi > N_NODES) hi = N_NODES;
    int s = 0;
    for (int i = lo; i < hi; i++) s += deg[i];
    red[t] = s;
    __syncthreads();
    for (int d = SCAN_T / 2; d > 0; d >>= 1) {
        if (t < d) red[t] += red[t + d];
        __syncthreads();
    }
    if (t == 0) bsum[b] = red[0];
}

__global__ __launch_bounds__(SCAN_T) void k_scanB(int* __restrict__ cur, int* __restrict__ off,
                                                  const int* __restrict__ bsum) {
    __shared__ int pre[SCAN_T];
    __shared__ int baseSh;
    const int t = threadIdx.x, b = blockIdx.x;
    const int g = b * SCAN_T + t;
    int lo = g * SCAN_C; if (lo > N_NODES) lo = N_NODES;
    int hi = lo + SCAN_C; if (hi > N_NODES) hi = N_NODES;
    int s = 0;
    for (int i = lo; i < hi; i++) s += cur[i];
    pre[t] = s;
    if (t == 0) {
        int acc = 0;
        for (int j = 0; j < b; j++) acc += bsum[j];
        baseSh = acc;
    }
    __syncthreads();
    for (int d = 1; d < SCAN_T; d <<= 1) {
        int v = (t >= d) ? pre[t - d] : 0;
        __syncthreads();
        pre[t] += v;
        __syncthreads();
    }
    int running = baseSh + pre[t] - s;
    for (int i = lo; i < hi; i++) {
        int d = cur[i];
        off[i] = running;
        cur[i] = running;
        running += d;
        if (i == N_NODES - 1) off[N_NODES] = running;
    }
}

// scatter packed (src, weight-bits) edges into CSR order
__global__ void k_scatter(const int* __restrict__ src, const int* __restrict__ dst,
                          const float* __restrict__ w, int* __restrict__ cursor,
                          int2* __restrict__ ep, int E) {
    int e = blockIdx.x * blockDim.x + threadIdx.x;
    if (e < E) {
        int d = dst[e];
        int pos = atomicAdd(&cursor[d], 1);
        ep[pos] = make_int2(src[e], __float_as_int(w[e]));
    }
}

// ---------------- gather helpers ----------------
// lane-parallel edge fetch + shfl broadcast, 8 outstanding row loads.

__device__ __forceinline__ void gatherF2(const int2* __restrict__ ep, int lo, int hi,
                                         const float* __restrict__ feats, int c,
                                         float& ax, float& ay)
{
    const int lane = threadIdx.x & 63;
    for (int base = lo; base < hi; base += 64) {
        const int cnt = min(hi - base, 64);
        int2 ev = make_int2(0, 0);
        if (lane < cnt) ev = ep[base + lane];
        int j = 0;
        for (; j + 8 <= cnt; j += 8) {
            int s0 = __shfl(ev.x, j + 0), s1 = __shfl(ev.x, j + 1);
            int s2 = __shfl(ev.x, j + 2), s3 = __shfl(ev.x, j + 3);
            int s4 = __shfl(ev.x, j + 4), s5 = __shfl(ev.x, j + 5);
            int s6 = __shfl(ev.x, j + 6), s7 = __shfl(ev.x, j + 7);
            float w0 = __int_as_float(__shfl(ev.y, j + 0));
            float w1 = __int_as_float(__shfl(ev.y, j + 1));
            float w2 = __int_as_float(__shfl(ev.y, j + 2));
            float w3 = __int_as_float(__shfl(ev.y, j + 3));
            float w4 = __int_as_float(__shfl(ev.y, j + 4));
            float w5 = __int_as_float(__shfl(ev.y, j + 5));
            float w6 = __int_as_float(__shfl(ev.y, j + 6));
            float w7 = __int_as_float(__shfl(ev.y, j + 7));
            float2 v0 = *(const float2*)(feats + (size_t)s0 * 128 + c);
            float2 v1 = *(const float2*)(feats + (size_t)s1 * 128 + c);
            float2 v2 = *(const float2*)(feats + (size_t)s2 * 128 + c);
            float2 v3 = *(const float2*)(feats + (size_t)s3 * 128 + c);
            float2 v4 = *(const float2*)(feats + (size_t)s4 * 128 + c);
            float2 v5 = *(const float2*)(feats + (size_t)s5 * 128 + c);
            float2 v6 = *(const float2*)(feats + (size_t)s6 * 128 + c);
            float2 v7 = *(const float2*)(feats + (size_t)s7 * 128 + c);
            ax = fmaf(w0, v0.x, ax); ay = fmaf(w0, v0.y, ay);
            ax = fmaf(w1, v1.x, ax); ay = fmaf(w1, v1.y, ay);
            ax = fmaf(w2, v2.x, ax); ay = fmaf(w2, v2.y, ay);
            ax = fmaf(w3, v3.x, ax); ay = fmaf(w3, v3.y, ay);
            ax = fmaf(w4, v4.x, ax); ay = fmaf(w4, v4.y, ay);
            ax = fmaf(w5, v5.x, ax); ay = fmaf(w5, v5.y, ay);
            ax = fmaf(w6, v6.x, ax); ay = fmaf(w6, v6.y, ay);
            ax = fmaf(w7, v7.x, ax); ay = fmaf(w7, v7.y, ay);
        }
        for (; j < cnt; j++) {
            int s = __shfl(ev.x, j);
            float w = __int_as_float(__shfl(ev.y, j));
            float2 v = *(const float2*)(feats + (size_t)s * 128 + c);
            ax = fmaf(w, v.x, ax); ay = fmaf(w, v.y, ay);
        }
    }
}

__device__ __forceinline__ void gatherF1(const int2* __restrict__ ep, int lo, int hi,
                                         const float* __restrict__ feats, int lane,
                                         float& a)
{
    for (int base = lo; base < hi; base += 64) {
        const int cnt = min(hi - base, 64);
        int2 ev = make_int2(0, 0);
        if (lane < cnt) ev = ep[base + lane];
        int j = 0;
        for (; j + 8 <= cnt; j += 8) {
            int s0 = __shfl(ev.x, j + 0), s1 = __shfl(ev.x, j + 1);
            int s2 = __shfl(ev.x, j + 2), s3 = __shfl(ev.x, j + 3);
            int s4 = __shfl(ev.x, j + 4), s5 = __shfl(ev.x, j + 5);
            int s6 = __shfl(ev.x, j + 6), s7 = __shfl(ev.x, j + 7);
            float w0 = __int_as_float(__shfl(ev.y, j + 0));
            float w1 = __int_as_float(__shfl(ev.y, j + 1));
            float w2 = __int_as_float(__shfl(ev.y, j + 2));
            float w3 = __int_as_float(__shfl(ev.y, j + 3));
            float w4 = __int_as_float(__shfl(ev.y, j + 4));
            float w5 = __int_as_float(__shfl(ev.y, j + 5));
            float w6 = __int_as_float(__shfl(ev.y, j + 6));
            float w7 = __int_as_float(__shfl(ev.y, j + 7));
            float v0 = feats[(size_t)s0 * 64 + lane];
            float v1 = feats[(size_t)s1 * 64 + lane];
            float v2 = feats[(size_t)s2 * 64 + lane];
            float v3 = feats[(size_t)s3 * 64 + lane];
            float v4 = feats[(size_t)s4 * 64 + lane];
            float v5 = feats[(size_t)s5 * 64 + lane];
            float v6 = feats[(size_t)s6 * 64 + lane];
            float v7 = feats[(size_t)s7 * 64 + lane];
            a = fmaf(w0, v0, a); a = fmaf(w1, v1, a);
            a = fmaf(w2, v2, a); a = fmaf(w3, v3, a);
            a = fmaf(w4, v4, a); a = fmaf(w5, v5, a);
            a = fmaf(w6, v6, a); a = fmaf(w7, v7, a);
        }
        for (; j < cnt; j++) {
            int s = __shfl(ev.x, j);
            float w = __int_as_float(__shfl(ev.y, j));
            a = fmaf(w, feats[(size_t)s * 64 + lane], a);
        }
    }
}

// ---------------- standalone SPMM ----------------
// MODE 0 (C=128): out = relu(acc + bias(aux)), duplicated into out2 (x0 copy)
// MODE 2 (C=64):  out = acc + bias(aux)
template <int C, int MODE>
__global__ __launch_bounds__(256) void k_spmm(
    const int* __restrict__ off, const int2* __restrict__ ep,
    const float* __restrict__ feats, const float* __restrict__ aux,
    float* __restrict__ out, float* __restrict__ out2)
{
    const int wave = threadIdx.x >> 6;
    const int lane = threadIdx.x & 63;
    const int node = blockIdx.x * 4 + wave;
    if (node >= N_NODES) return;
    const int lo = off[node], hi = off[node + 1];

    if constexpr (C == 128) {
        float ax = 0.f, ay = 0.f;
        const int c = lane * 2;
        gatherF2(ep, lo, hi, feats, c, ax, ay);
        float r0 = fmaxf(ax + aux[c], 0.f);
        float r1 = fmaxf(ay + aux[c + 1], 0.f);
        float2 r; r.x = r0; r.y = r1;
        *(float2*)(out  + (size_t)node * 128 + c) = r;
        *(float2*)(out2 + (size_t)node * 128 + c) = r;
    } else {
        float a = 0.f;
        gatherF1(ep, lo, hi, feats, lane, a);
        out[(size_t)node * 64 + lane] = a + aux[lane];
    }
}

// ---------------- standalone GEMM: out[M x N] = A[M x 128] @ W[128 x N] ----------------
template <int N>
__global__ __launch_bounds__(256) void k_gemm(
    const float* __restrict__ A, const float* __restrict__ W,
    float* __restrict__ out, int M)
{
    constexpr int CPT = N / 32;
    __shared__ float As[32][128];
    const int tid = threadIdx.x;
    const int row0 = blockIdx.x * 32;

    {
        const float4* srcp = (const float4*)(A + (size_t)row0 * 128);
        float4* dl = (float4*)(&As[0][0]);
        #pragma unroll
        for (int it = 0; it < 4; it++) {
            int idx = tid + it * 256;
            int r = idx >> 5;
            float4 v;
            if (row0 + r < M) v = srcp[idx];
            else v = make_float4(0.f, 0.f, 0.f, 0.f);
            dl[idx] = v;
        }
    }
    __syncthreads();

    const int rg = tid >> 5;
    const int c0 = (tid & 31) * CPT;

    float acc[4][CPT];
    #pragma unroll
    for (int i = 0; i < 4; i++)
        #pragma unroll
        for (int j = 0; j < CPT; j++) acc[i][j] = 0.f;

    #pragma unroll 4
    for (int k = 0; k < 128; k++) {
        float a0 = As[rg * 4 + 0][k];
        float a1 = As[rg * 4 + 1][k];
        float a2 = As[rg * 4 + 2][k];
        float a3 = As[rg * 4 + 3][k];
        float w[CPT];
        if constexpr (CPT == 4) {
            float4 wv = *(const float4*)(W + (size_t)k * N + c0);
            w[0] = wv.x; w[1] = wv.y; w[2] = wv.z; w[3] = wv.w;
        } else {
            float2 wv = *(const float2*)(W + (size_t)k * N + c0);
            w[0] = wv.x; w[1] = wv.y;
        }
        #pragma unroll
        for (int j = 0; j < CPT; j++) {
            acc[0][j] = fmaf(a0, w[j], acc[0][j]);
            acc[1][j] = fmaf(a1, w[j], acc[1][j]);
            acc[2][j] = fmaf(a2, w[j], acc[2][j]);
            acc[3][j] = fmaf(a3, w[j], acc[3][j]);
        }
    }

    #pragma unroll
    for (int i = 0; i < 4; i++) {
        int r = row0 + rg * 4 + i;
        if (r < M) {
            #pragma unroll
            for (int j = 0; j < CPT; j++)
                out[(size_t)r * N + c0 + j] = acc[i][j];
        }
    }
}

// ---------------- fused layer ----------------
// h_out = relu((1-beta)*t + beta*(t @ W)),  t = 0.5*spmm(h_in) + 0.5*x0
__global__ __launch_bounds__(256) void k_layer(
    const int* __restrict__ off, const int2* __restrict__ ep,
    const float* __restrict__ h_in, const float* __restrict__ x0, const float* __restrict__ W,
    float* __restrict__ h_out, float beta)
{
    __shared__ float As[32][128];
    const int tid = threadIdx.x;
    const int wave = tid >> 6, lane = tid & 63;
    const int row0 = blockIdx.x * 32;
    const int c = lane * 2;

    // phase 1: spmm -> t -> LDS (each wave: 8 nodes)
    #pragma unroll 1
    for (int i = 0; i < 8; i++) {
        const int r = wave * 8 + i;
        const int node = row0 + r;
        float ax = 0.f, ay = 0.f;
        if (node < N_NODES) {
            gatherF2(ep, off[node], off[node + 1], h_in, c, ax, ay);
            float2 x0v = *(const float2*)(x0 + (size_t)node * 128 + c);
            ax = 0.5f * ax + 0.5f * x0v.x;
            ay = 0.5f * ay + 0.5f * x0v.y;
        }
        float2 t; t.x = ax; t.y = ay;
        *(float2*)(&As[r][c]) = t;
    }
    __syncthreads();

    // phase 2: gemm + GCNII epilogue
    const int rg = tid >> 5;
    const int c0 = (tid & 31) * 4;

    float acc[4][4];
    #pragma unroll
    for (int i = 0; i < 4; i++)
        #pragma unroll
        for (int j = 0; j < 4; j++) acc[i][j] = 0.f;

    #pragma unroll 4
    for (int k = 0; k < 128; k++) {
        float a0 = As[rg * 4 + 0][k];
        float a1 = As[rg * 4 + 1][k];
        float a2 = As[rg * 4 + 2][k];
        float a3 = As[rg * 4 + 3][k];
        float4 wv = *(const float4*)(W + (size_t)k * 128 + c0);
        float w[4] = {wv.x, wv.y, wv.z, wv.w};
        #pragma unroll
        for (int j = 0; j < 4; j++) {
            acc[0][j] = fmaf(a0, w[j], acc[0][j]);
            acc[1][j] = fmaf(a1, w[j], acc[1][j]);
            acc[2][j] = fmaf(a2, w[j], acc[2][j]);
            acc[3][j] = fmaf(a3, w[j], acc[3][j]);
        }
    }

    const float omb = 1.f - beta;
    #pragma unroll
    for (int i = 0; i < 4; i++) {
        int r = row0 + rg * 4 + i;
        if (r < N_NODES) {
            #pragma unroll
            for (int j = 0; j < 4; j++) {
                float t = As[rg * 4 + i][c0 + j];
                float v = fmaxf(omb * t + beta * acc[i][j], 0.f);
                h_out[(size_t)r * 128 + c0 + j] = v;
            }
        }
    }
}

// ---------------- launch ----------------

extern "C" void kernel_launch(void* const* d_in, const int* in_sizes, int n_in,
                              void* d_out, int out_size, void* d_ws, size_t ws_size,
                              hipStream_t stream)
{
    const float* x     = (const float*)d_in[0];
    const int*   ei    = (const int*)d_in[1];
    const float* ew    = (const float*)d_in[2];
    const float* W_in  = (const float*)d_in[3];
    const float* b_in  = (const float*)d_in[4];
    const float* W_lay = (const float*)d_in[5];
    const float* W_out = (const float*)d_in[6];
    const float* b_out = (const float*)d_in[7];
    float* out = (float*)d_out;

    const int* src = ei;
    const int* dst = ei + N_EDGES;

    char* p = (char*)d_ws;
    auto alloc = [&](size_t bytes) -> char* {
        char* q = p;
        p += (bytes + 255) & ~(size_t)255;
        return q;
    };
    int*   cursor = (int*)alloc((size_t)N_NODES * 4);
    int*   off    = (int*)alloc((size_t)(N_NODES + 1) * 4);
    int2*  ep     = (int2*)alloc((size_t)N_EDGES * 8);
    int*   bsum   = (int*)alloc((size_t)SCAN_B * 4);
    float* bufT   = (float*)alloc((size_t)N_NODES * HID * 4);
    float* bufH   = (float*)alloc((size_t)N_NODES * HID * 4);
    float* bufX0  = (float*)alloc((size_t)N_NODES * HID * 4);

    // CSR build
    k_zero<<<(N_NODES + 255) / 256, 256, 0, stream>>>(cursor, N_NODES);
    k_count<<<(N_EDGES + 255) / 256, 256, 0, stream>>>(dst, cursor, N_EDGES);
    k_scanA<<<SCAN_B, SCAN_T, 0, stream>>>(cursor, bsum);
    k_scanB<<<SCAN_B, SCAN_T, 0, stream>>>(cursor, off, bsum);
    k_scatter<<<(N_EDGES + 255) / 256, 256, 0, stream>>>(src, dst, ew, cursor, ep, N_EDGES);

    const int gemmGrid = (N_NODES + 31) / 32;
    const int spmmGrid = (N_NODES + 3) / 4;

    // z = x @ W_in -> bufT
    k_gemm<128><<<gemmGrid, 256, 0, stream>>>(x, W_in, bufT, N_NODES);
    // h = relu(spmm(z) + b_in) -> bufH, copy -> bufX0
    k_spmm<128, 0><<<spmmGrid, 256, 0, stream>>>(off, ep, bufT, b_in, bufH, bufX0);

    float* hin = bufH;
    float* hout = bufT;
    for (int l = 0; l < NLAYERS; l++) {
        float beta = logf(1.0f / (float)(l + 1) + 1.0f);
        k_layer<<<gemmGrid, 256, 0, stream>>>(off, ep, hin, bufX0,
                                              W_lay + (size_t)l * HID * HID, hout, beta);
        float* tmp = hin; hin = hout; hout = tmp;
    }

    // y = h @ W_out
    k_gemm<64><<<gemmGrid, 256, 0, stream>>>(hin, W_out, hout, N_NODES);
    // out = spmm(y) + b_out
    k_spmm<64, 2><<<spmmGrid, 256, 0, stream>>>(off, ep, hout, b_out, out, nullptr);
}